// Round 3
// baseline (319.413 us; speedup 1.0000x reference)
//
#include <hip/hip_runtime.h>
#include <hip/hip_bf16.h>

// N=10000, E=50000, IN=32, H=64 (derived from in_sizes defensively).
//
// Algebraic refactor: theta[e] = sum_k ea[e,k]*W_k + B  (W_k,B: [64,64])
//   => msg[e] = sum_k ea[e,k]*(h@W_k)[src] + (h@B)[src]
// Per iteration:
//   ZZ[N,576] = h @ [W0|W1|W2|W3|B|root_w|w_hh^T]   (gh hoisted since h==out)
//   agg via dst-CSR (built once per launch, atomic-free aggregation),
//   m = relu(agg + ZZ[:,320:384] + conv_b)  (fused into aggregation kernel)
//   gi = m @ w_ih^T ; GRU elementwise epilogue.

#define AP 65   // a/m LDS stride: (65*j + r) % 32 == (j+r)%32 -> conflict-free writes
#define WP 68   // w LDS stride: float4-aligned rows; c-fast writes conflict-free

__device__ __forceinline__ float sigmoidf_(float x) {
    return 1.0f / (1.0f + __expf(-x));
}
__device__ __forceinline__ float tanhf_(float x) {
    return 2.0f / (1.0f + __expf(-2.0f * x)) - 1.0f;
}

// ---------------- lin0: h = relu(x @ lin0_w + b) ------------------------------------
__global__ __launch_bounds__(256) void lin0_k(const float* __restrict__ x,
                                              const float* __restrict__ w,
                                              const float* __restrict__ b,
                                              float* __restrict__ h, int N) {
    int gid = blockIdx.x * 256 + threadIdx.x;
    int n = gid >> 6, l = gid & 63;
    if (n >= N) return;
    float acc = b[l];
#pragma unroll
    for (int j = 0; j < 32; ++j) acc = fmaf(x[n * 32 + j], w[j * 64 + l], acc);
    h[n * 64 + l] = fmaxf(acc, 0.0f);
}

// ---------------- CSR build (once per launch) ---------------------------------------
__global__ __launch_bounds__(256) void count_k(const int* __restrict__ ei,
                                               int* __restrict__ dcnt, int E) {
    int e = blockIdx.x * 256 + threadIdx.x;
    if (e < E) atomicAdd(dcnt + ei[E + e], 1);
}

__global__ __launch_bounds__(1024) void scan_k(const int* __restrict__ dcnt,
                                               int* __restrict__ rowptr,
                                               int* __restrict__ cursor, int N) {
    __shared__ int part[1024];
    const int t = threadIdx.x;
    const int per = (N + 1023) >> 10;
    const int s0 = t * per;
    const int e0 = min(s0 + per, N);
    int sum = 0;
    for (int i = s0; i < e0; ++i) sum += dcnt[i];
    part[t] = sum;
    __syncthreads();
    for (int d = 1; d < 1024; d <<= 1) {  // inclusive Hillis-Steele
        int u = (t >= d) ? part[t - d] : 0;
        __syncthreads();
        part[t] += u;
        __syncthreads();
    }
    int off = part[t] - sum;  // exclusive prefix of this thread's chunk
    for (int i = s0; i < e0; ++i) {
        rowptr[i] = off;
        cursor[i] = off;
        off += dcnt[i];
    }
    if (e0 == N && s0 < N) rowptr[N] = off;
}

__global__ __launch_bounds__(256) void fill_k(const int* __restrict__ ei,
                                              const float4* __restrict__ ea,
                                              int* __restrict__ cursor,
                                              int* __restrict__ esrc,
                                              float4* __restrict__ eattr, int E) {
    int e = blockIdx.x * 256 + threadIdx.x;
    if (e >= E) return;
    int d = ei[E + e];
    int pos = atomicAdd(cursor + d, 1);
    esrc[pos] = ei[e];
    eattr[pos] = ea[e];
}

// ---------------- kernel A: ZZ[N,576] = h[N,64] @ Wcat[64,576] ----------------------
// blockIdx.y = y in {0,1,2}: col-blocks cb = 3y + {0,1,2}
//   cb 0..3 -> nn_w k ; cb 4 -> nn_b ; cb 5 -> root_w ; cb 6..8 -> w_hh^T
__global__ __launch_bounds__(256) void gemm_a3(const float* __restrict__ h,
                                               const float* __restrict__ nn_w,
                                               const float* __restrict__ nn_b,
                                               const float* __restrict__ root_w,
                                               const float* __restrict__ w_hh,
                                               float* __restrict__ ZZ, int N) {
    __shared__ float a_lds[64 * AP];
    __shared__ float w_lds[3 * 64 * WP];
    const int n0 = blockIdx.x * 64;
    const int y = blockIdx.y;
    const int tid = threadIdx.x;

    // a_lds[j][r] = h[n0+r, j]  (coalesced global, conflict-free LDS writes)
    for (int idx = tid; idx < 4096; idx += 256) {
        int r = idx >> 6, j = idx & 63;
        int n = n0 + r;
        a_lds[j * AP + r] = (n < N) ? h[n * 64 + j] : 0.0f;
    }
    // stage 3 weight blocks: w_lds[s][j][c] = Wcat[j, (3y+s)*64+c]
#pragma unroll
    for (int s = 0; s < 3; ++s) {
        int cb = y * 3 + s;
        float* wl = w_lds + s * 64 * WP;
        if (cb < 6) {
            for (int idx = tid; idx < 4096; idx += 256) {
                int j = idx >> 6, c = idx & 63;  // c fast: coalesced + conflict-free
                float v;
                if (cb < 4) v = nn_w[cb * 4096 + j * 64 + c];
                else if (cb == 4) v = nn_b[j * 64 + c];
                else v = root_w[j * 64 + c];
                wl[j * WP + c] = v;
            }
        } else {
            int g0 = (cb - 6) * 64;
            for (int idx = tid; idx < 4096; idx += 256) {
                int c = idx >> 6, j = idx & 63;  // j fast: coalesced w_hh reads
                wl[j * WP + c] = w_hh[(g0 + c) * 64 + j];
            }
        }
    }
    __syncthreads();

    const int row_t = tid >> 4, col_t = tid & 15;
    const int r0 = row_t * 4, c0 = col_t * 4;
    float acc[3][4][4] = {};
#pragma unroll 4
    for (int j = 0; j < 64; ++j) {
        float av[4];
#pragma unroll
        for (int rr = 0; rr < 4; ++rr) av[rr] = a_lds[j * AP + r0 + rr];
#pragma unroll
        for (int s = 0; s < 3; ++s) {
            const float4 w4 = *(const float4*)(w_lds + s * 64 * WP + j * WP + c0);
            const float wv[4] = {w4.x, w4.y, w4.z, w4.w};
#pragma unroll
            for (int rr = 0; rr < 4; ++rr)
#pragma unroll
                for (int cc = 0; cc < 4; ++cc)
                    acc[s][rr][cc] = fmaf(av[rr], wv[cc], acc[s][rr][cc]);
        }
    }
#pragma unroll
    for (int s = 0; s < 3; ++s) {
        const int cbase = (y * 3 + s) * 64 + c0;
#pragma unroll
        for (int rr = 0; rr < 4; ++rr) {
            int n = n0 + r0 + rr;
            if (n < N) {
                float4 v = make_float4(acc[s][rr][0], acc[s][rr][1], acc[s][rr][2],
                                       acc[s][rr][3]);
                *(float4*)(ZZ + (size_t)n * 576 + cbase) = v;
            }
        }
    }
}

// ---------------- aggregation (CSR, atomic-free) + m = relu(...) --------------------
__global__ __launch_bounds__(256) void agg_k(const int* __restrict__ rowptr,
                                             const int* __restrict__ esrc,
                                             const float4* __restrict__ eattr,
                                             const float* __restrict__ ZZ,
                                             const float* __restrict__ conv_b,
                                             float* __restrict__ m, int N) {
    int n = blockIdx.x * 4 + (threadIdx.x >> 6);
    int lane = threadIdx.x & 63;
    if (n >= N) return;
    const int b = rowptr[n], e = rowptr[n + 1];
    float acc = 0.0f;
    int i = b;
    for (; i + 2 <= e; i += 2) {  // unroll-2: both edges' loads issue together
        int s0 = esrc[i], s1 = esrc[i + 1];
        float4 a0 = eattr[i], a1 = eattr[i + 1];
        const float* z0 = ZZ + (size_t)s0 * 576 + lane;
        const float* z1 = ZZ + (size_t)s1 * 576 + lane;
        float p0 = z0[0], p1 = z0[64], p2 = z0[128], p3 = z0[192], p4 = z0[256];
        float q0 = z1[0], q1 = z1[64], q2 = z1[128], q3 = z1[192], q4 = z1[256];
        acc += fmaf(a0.x, p0, fmaf(a0.y, p1, fmaf(a0.z, p2, fmaf(a0.w, p3, p4))));
        acc += fmaf(a1.x, q0, fmaf(a1.y, q1, fmaf(a1.z, q2, fmaf(a1.w, q3, q4))));
    }
    if (i < e) {
        int s0 = esrc[i];
        float4 a0 = eattr[i];
        const float* z0 = ZZ + (size_t)s0 * 576 + lane;
        acc += fmaf(a0.x, z0[0], fmaf(a0.y, z0[64],
                    fmaf(a0.z, z0[128], fmaf(a0.w, z0[192], z0[256]))));
    }
    float v = acc + ZZ[(size_t)n * 576 + 320 + lane] + conv_b[lane];
    m[(size_t)n * 64 + lane] = fmaxf(v, 0.0f);
}

// ---------------- fused gi GEMM -> GRU elementwise ----------------------------------
__global__ __launch_bounds__(256) void gru2(const float* __restrict__ m,
                                            const float* __restrict__ ZZ,
                                            const float* __restrict__ w_ih,
                                            const float* __restrict__ b_ih,
                                            const float* __restrict__ b_hh,
                                            float* __restrict__ h,
                                            float* __restrict__ out_final, int N) {
    __shared__ float m_lds[64 * AP];
    __shared__ float w_lds[3 * 64 * WP];
    const int n0 = blockIdx.x * 64;
    const int tid = threadIdx.x;

    for (int idx = tid; idx < 4096; idx += 256) {
        int r = idx >> 6, j = idx & 63;
        int n = n0 + r;
        m_lds[j * AP + r] = (n < N) ? m[(size_t)n * 64 + j] : 0.0f;
    }
#pragma unroll
    for (int cb = 0; cb < 3; ++cb) {
        float* wl = w_lds + cb * 64 * WP;
        for (int idx = tid; idx < 4096; idx += 256) {
            int c = idx >> 6, j = idx & 63;  // j fast: coalesced w_ih reads
            wl[j * WP + c] = w_ih[(cb * 64 + c) * 64 + j];
        }
    }
    __syncthreads();

    const int row_t = tid >> 4, col_t = tid & 15;
    const int r0 = row_t * 4, c0 = col_t * 4;
    float acc[3][4][4] = {};
#pragma unroll 4
    for (int j = 0; j < 64; ++j) {
        float av[4];
#pragma unroll
        for (int rr = 0; rr < 4; ++rr) av[rr] = m_lds[j * AP + r0 + rr];
#pragma unroll
        for (int cb = 0; cb < 3; ++cb) {
            const float4 w4 = *(const float4*)(w_lds + cb * 64 * WP + j * WP + c0);
            const float wv[4] = {w4.x, w4.y, w4.z, w4.w};
#pragma unroll
            for (int rr = 0; rr < 4; ++rr)
#pragma unroll
                for (int cc = 0; cc < 4; ++cc)
                    acc[cb][rr][cc] = fmaf(av[rr], wv[cc], acc[cb][rr][cc]);
        }
    }

#pragma unroll
    for (int rr = 0; rr < 4; ++rr) {
        int n = n0 + r0 + rr;
        if (n >= N) continue;
        const float4 ghr4 = *(const float4*)(ZZ + (size_t)n * 576 + 384 + c0);
        const float4 ghz4 = *(const float4*)(ZZ + (size_t)n * 576 + 448 + c0);
        const float4 ghn4 = *(const float4*)(ZZ + (size_t)n * 576 + 512 + c0);
        const float4 hv4 = *(const float4*)(h + (size_t)n * 64 + c0);
        const float ghr[4] = {ghr4.x, ghr4.y, ghr4.z, ghr4.w};
        const float ghz[4] = {ghz4.x, ghz4.y, ghz4.z, ghz4.w};
        const float ghn[4] = {ghn4.x, ghn4.y, ghn4.z, ghn4.w};
        const float hv[4] = {hv4.x, hv4.y, hv4.z, hv4.w};
        float hnew[4];
#pragma unroll
        for (int cc = 0; cc < 4; ++cc) {
            int l = c0 + cc;
            float gir = acc[0][rr][cc] + b_ih[l];
            float giz = acc[1][rr][cc] + b_ih[64 + l];
            float gin = acc[2][rr][cc] + b_ih[128 + l];
            float hr = ghr[cc] + b_hh[l];
            float hz = ghz[cc] + b_hh[64 + l];
            float hn = ghn[cc] + b_hh[128 + l];
            float rg = sigmoidf_(gir + hr);
            float zg = sigmoidf_(giz + hz);
            float ng = tanhf_(gin + rg * hn);
            hnew[cc] = (1.0f - zg) * ng + zg * hv[cc];
        }
        float4 o = make_float4(hnew[0], hnew[1], hnew[2], hnew[3]);
        *(float4*)(h + (size_t)n * 64 + c0) = o;
        if (out_final) *(float4*)(out_final + (size_t)n * 64 + c0) = o;
    }
}

extern "C" void kernel_launch(void* const* d_in, const int* in_sizes, int n_in,
                              void* d_out, int out_size, void* d_ws, size_t ws_size,
                              hipStream_t stream) {
    const float* x      = (const float*)d_in[0];
    const int*   ei     = (const int*)d_in[1];
    const float* ea     = (const float*)d_in[2];
    const float* lin0_w = (const float*)d_in[3];
    const float* lin0_b = (const float*)d_in[4];
    const float* nn_w   = (const float*)d_in[5];
    const float* nn_b   = (const float*)d_in[6];
    const float* root_w = (const float*)d_in[7];
    const float* conv_b = (const float*)d_in[8];
    const float* gw_ih  = (const float*)d_in[9];
    const float* gw_hh  = (const float*)d_in[10];
    const float* gb_ih  = (const float*)d_in[11];
    const float* gb_hh  = (const float*)d_in[12];

    const int N = in_sizes[0] / 32;
    const int E = in_sizes[1] / 2;

    // workspace layout (16B-aligned blocks first)
    float* eattr = (float*)d_ws;                       // [E,4]
    float* ZZ    = eattr + (size_t)E * 4;              // [N,576]
    float* h     = ZZ + (size_t)N * 576;               // [N,64]
    float* m     = h + (size_t)N * 64;                 // [N,64]
    int* rowptr  = (int*)(m + (size_t)N * 64);         // [N+1]
    int* cursor  = rowptr + (N + 1);                   // [N]
    int* esrc    = cursor + N;                         // [E]
    int* dcnt    = esrc + E;                           // [N]

    const int RB = (N + 63) / 64;

    (void)hipMemsetAsync(dcnt, 0, (size_t)N * sizeof(int), stream);
    count_k<<<(E + 255) / 256, 256, 0, stream>>>(ei, dcnt, E);
    lin0_k<<<(N * 64 + 255) / 256, 256, 0, stream>>>(x, lin0_w, lin0_b, h, N);
    scan_k<<<1, 1024, 0, stream>>>(dcnt, rowptr, cursor, N);
    fill_k<<<(E + 255) / 256, 256, 0, stream>>>(ei, (const float4*)ea, cursor, esrc,
                                                (float4*)eattr, E);

    for (int it = 0; it < 3; ++it) {
        gemm_a3<<<dim3(RB, 3), 256, 0, stream>>>(h, nn_w, nn_b, root_w, gw_hh, ZZ, N);
        agg_k<<<(N + 3) / 4, 256, 0, stream>>>(rowptr, esrc, (const float4*)eattr, ZZ,
                                               conv_b, m, N);
        gru2<<<RB, 256, 0, stream>>>(m, ZZ, gw_ih, gb_ih, gb_hh, h,
                                     (it == 2) ? (float*)d_out : nullptr, N);
    }
}